// Round 6
// baseline (370.004 us; speedup 1.0000x reference)
//
#include <hip/hip_runtime.h>
#include <math.h>

#define D   1024
#define H   16
#define HD  64
#define SEQ 2048
#define LL  8
#define SCALE 0.125f
#define TZS 1048   // tz LDS row stride (bank-spread, 16B-aligned)

typedef __attribute__((ext_vector_type(8))) __bf16 bf16x8;
typedef __attribute__((ext_vector_type(4))) float floatx4;
typedef __attribute__((ext_vector_type(8))) unsigned short ushort8;

__device__ inline unsigned short f32_to_bf16(float f) {
    unsigned int u = __builtin_bit_cast(unsigned int, f);
    u += 0x7FFF + ((u >> 16) & 1);
    return (unsigned short)(u >> 16);
}
__device__ inline float bf2f(unsigned short u) {
    unsigned int x = (unsigned int)u << 16;
    return __builtin_bit_cast(float, x);
}
__device__ inline void load_lds16(const void* g, void* l) {
    __builtin_amdgcn_global_load_lds(
        (__attribute__((address_space(1))) void*)g,
        (__attribute__((address_space(3))) void*)l, 16, 0, 0);
}
__device__ inline void xcd_swizzle(int& bx, int& by) {
    const int gx   = gridDim.x;
    const int lin  = blockIdx.y * gx + blockIdx.x;
    const int nblk = gx * gridDim.y;
    const int virt = (lin & 7) * (nblk >> 3) + (lin >> 3);
    bx = virt % gx;
    by = virt / gx;
}

// ---------------------------------------------------------------------------
// prep: LN(reproject(pv)) | f32->bf16 of x, [Wqkv|Wcol]->W4, Wout | bias b4 |
//       WkT (64x64-tiled transpose of Wqkv rows 1024..2047)
// ---------------------------------------------------------------------------
#define NQ_X    524288
#define NQ_WQKV 786432
#define NQ_WC   262144
#define LN_BLK  16384
#define CVT_BLK 7168
#define TR_BLK  256
#define PREP_GRID (LN_BLK + CVT_BLK + 4 + TR_BLK)

__global__ __launch_bounds__(256) void prep_kernel(
    const float* __restrict__ pv, const float* __restrict__ x,
    const float* __restrict__ Wqkv, const float* __restrict__ Wcol,
    const float* __restrict__ Wout, const float* __restrict__ bqkv,
    const float* __restrict__ bcol,
    unsigned short* __restrict__ ri, unsigned short* __restrict__ xb,
    unsigned short* __restrict__ W4b, unsigned short* __restrict__ Woutb,
    float* __restrict__ b4, unsigned short* __restrict__ WkT)
{
    __shared__ float ft[64][65];
    const int b = blockIdx.x;
    const int t = threadIdx.x;
    if (b < LN_BLK) {
        const int r = b;
        const int s = r >> 3, l = r & 7;
        const int h = t >> 4, e = (t & 15) * 4;
        const size_t src = (size_t)l * (H * SEQ * HD) + (size_t)h * (SEQ * HD)
                         + (size_t)s * HD + e;
        float4 v = *(const float4*)(pv + src);
        float sum = v.x + v.y + v.z + v.w;
        float sq  = v.x * v.x + v.y * v.y + v.z * v.z + v.w * v.w;
#pragma unroll
        for (int off = 32; off; off >>= 1) {
            sum += __shfl_xor(sum, off);
            sq  += __shfl_xor(sq, off);
        }
        __shared__ float red[8];
        if ((t & 63) == 0) { red[(t >> 6) * 2] = sum; red[(t >> 6) * 2 + 1] = sq; }
        __syncthreads();
        sum = red[0] + red[2] + red[4] + red[6];
        sq  = red[1] + red[3] + red[5] + red[7];
        const float mean = sum * (1.f / 1024.f);
        const float var  = sq * (1.f / 1024.f) - mean * mean;
        const float rstd = rsqrtf(var + 1e-5f);
        ushort4 o;
        o.x = f32_to_bf16((v.x - mean) * rstd);
        o.y = f32_to_bf16((v.y - mean) * rstd);
        o.z = f32_to_bf16((v.z - mean) * rstd);
        o.w = f32_to_bf16((v.w - mean) * rstd);
        *(ushort4*)(ri + (size_t)r * D + t * 4) = o;
    } else if (b < LN_BLK + CVT_BLK) {
        const int i = (b - LN_BLK) * 256 + t;
        const float* src; unsigned short* dst; int off;
        if (i < NQ_X) {
            src = x; dst = xb; off = i;
        } else if (i < NQ_X + NQ_WQKV) {
            src = Wqkv; dst = W4b; off = i - NQ_X;
        } else if (i < NQ_X + NQ_WQKV + NQ_WC) {
            src = Wcol; dst = W4b + (size_t)NQ_WQKV * 4; off = i - NQ_X - NQ_WQKV;
        } else {
            src = Wout; dst = Woutb; off = i - NQ_X - NQ_WQKV - NQ_WC;
        }
        float4 v = ((const float4*)src)[off];
        ushort4 o;
        o.x = f32_to_bf16(v.x); o.y = f32_to_bf16(v.y);
        o.z = f32_to_bf16(v.z); o.w = f32_to_bf16(v.w);
        ((ushort4*)dst)[off] = o;
    } else if (b < LN_BLK + CVT_BLK + 4) {
        const int q = (b - LN_BLK - CVT_BLK) * 256 + t;
        float4 v = (q < 768) ? ((const float4*)bqkv)[q] : ((const float4*)bcol)[q - 768];
        ((float4*)b4)[q] = v;
    } else {
        // WkT[k][e'] = Wk[e'][k], Wk = Wqkv rows 1024..2047. 64x64 tiles.
        const int tt = b - LN_BLK - CVT_BLK - 4;
        const int kt = tt >> 4, et = tt & 15;
        const int r = t >> 2, c16 = (t & 3) * 16;
        const float* srow = Wqkv + (size_t)(1024 + et * 64 + r) * 1024 + kt * 64 + c16;
#pragma unroll
        for (int j = 0; j < 4; j++) {
            float4 v = *(const float4*)(srow + j * 4);
            ft[r][c16 + j * 4 + 0] = v.x; ft[r][c16 + j * 4 + 1] = v.y;
            ft[r][c16 + j * 4 + 2] = v.z; ft[r][c16 + j * 4 + 3] = v.w;
        }
        __syncthreads();
        const int rk = t >> 2, ec = (t & 3) * 16;
        unsigned short* orow = WkT + (size_t)(kt * 64 + rk) * 1024 + et * 64 + ec;
#pragma unroll
        for (int half = 0; half < 2; half++) {
            ushort8 o;
#pragma unroll
            for (int j = 0; j < 8; j++)
                o[j] = f32_to_bf16(ft[ec + half * 8 + j][rk]);
            *(ushort8*)(orow + half * 8) = o;
        }
    }
}

// ---------------------------------------------------------------------------
// bf16 MFMA GEMM: C[M,N] = A[M,K] @ W[N,K]^T + bias[N].
// ---------------------------------------------------------------------------
template <typename CT>
__global__ __launch_bounds__(256) void gemm_bf16_kernel(
    const unsigned short* __restrict__ A, const unsigned short* __restrict__ W,
    const float* __restrict__ bias, CT* __restrict__ C, int K, int N)
{
    __shared__ unsigned short As[128 * 32];
    __shared__ unsigned short Ws[128 * 32];
    const int t    = threadIdx.x;
    const int wave = t >> 6, lane = t & 63;
    const int wm   = wave >> 1, wn = wave & 1;
    int bx, by;
    xcd_swizzle(bx, by);
    const int m0 = by * 128, n0 = bx * 128;

    floatx4 acc[4][4];
#pragma unroll
    for (int i = 0; i < 4; i++)
#pragma unroll
        for (int j = 0; j < 4; j++) acc[i][j] = (floatx4)0.f;

    const int lrow = lane >> 2;
    const int lcol = (lane & 3) * 8;
    const unsigned short* Ag = A + (size_t)(m0 + wave * 32 + lrow) * K + lcol;
    const unsigned short* Wg = W + (size_t)(n0 + wave * 32 + lrow) * K + lcol;
    unsigned short* Asw = &As[wave * 32 * 32];
    unsigned short* Wsw = &Ws[wave * 32 * 32];
    const size_t rowskip = (size_t)16 * K;

    const int arow  = lane & 15;
    const int aquad = (lane >> 4) * 8;

    for (int k0 = 0; k0 < K; k0 += 32) {
        load_lds16(Ag + k0,           Asw);
        load_lds16(Ag + k0 + rowskip, Asw + 16 * 32);
        load_lds16(Wg + k0,           Wsw);
        load_lds16(Wg + k0 + rowskip, Wsw + 16 * 32);
        __syncthreads();

        bf16x8 af[4], wf[4];
#pragma unroll
        for (int mi = 0; mi < 4; mi++)
            af[mi] = *(const bf16x8*)&As[(wm * 64 + mi * 16 + arow) * 32 + aquad];
#pragma unroll
        for (int ni = 0; ni < 4; ni++)
            wf[ni] = *(const bf16x8*)&Ws[(wn * 64 + ni * 16 + arow) * 32 + aquad];
#pragma unroll
        for (int mi = 0; mi < 4; mi++)
#pragma unroll
            for (int ni = 0; ni < 4; ni++)
                acc[mi][ni] = __builtin_amdgcn_mfma_f32_16x16x32_bf16(
                    af[mi], wf[ni], acc[mi][ni], 0, 0, 0);
        __syncthreads();
    }

    const int crow = (lane >> 4) * 4, ccol = lane & 15;
#pragma unroll
    for (int mi = 0; mi < 4; mi++) {
#pragma unroll
        for (int ni = 0; ni < 4; ni++) {
            const int gm = m0 + wm * 64 + mi * 16 + crow;
            const int gn = n0 + wn * 64 + ni * 16 + ccol;
            const float bb = bias[gn];
#pragma unroll
            for (int r = 0; r < 4; r++) {
                float v = acc[mi][ni][r] + bb;
                if constexpr (sizeof(CT) == 2)
                    C[(size_t)(gm + r) * N + gn] = (CT)f32_to_bf16(v);
                else
                    C[(size_t)(gm + r) * N + gn] = v;
            }
        }
    }
}

// ---------------------------------------------------------------------------
// Memory-key attention partial (low-rank restructure).
// Block = 16 queries x 2 heads; 1024 blocks. Per (s,h):
//   t = Wk_h^T qcol_h (MFMA)  ->  score_l = (t . ri[s,l] + qcol_h.bk_h)*SCALE
//   softmax partial (m2,l2)   ->  z = sum_l p_l ri[s,l] (VALU)
//   O2 = Wv_h z + l2*bv_h (MFMA)  -> third softmax-split partial.
// ---------------------------------------------------------------------------
__global__ __launch_bounds__(256, 2) void mem_attn_kernel(
    const unsigned short* __restrict__ qkv4, const unsigned short* __restrict__ ri,
    const unsigned short* __restrict__ WkT, const unsigned short* __restrict__ Wv,
    const float* __restrict__ bk, const float* __restrict__ bv,
    float* __restrict__ Omem, float2* __restrict__ mlmem)
{
    const int t = threadIdx.x;
    const int w = t >> 6, lane = t & 63;
    const int lrow = lane & 15, quad = lane >> 4, lk = quad * 8;
    const int b  = blockIdx.x;
    const int sg = (b & 7) + 8 * ((b >> 3) & 15);   // XCD-colocated by sg
    const int hg = b >> 7;
    const int s0 = sg * 16;
    const int r0 = s0 * 8;

    __shared__ unsigned short tz[2][16][TZS];  // t, later z (per head)
    __shared__ float s_sc[2][16][8];
    __shared__ float s_c[2][16];
    __shared__ float s_p[2][16][8];
    __shared__ float s_l2[2][16];

    // ---- A: bias dots c[hh][s] = qcol_h[s] . bk_h ----
    {
        const int hh = t >> 7, s = (t >> 3) & 15, g = t & 7;
        const int h = hg * 2 + hh;
        const unsigned short* qc = qkv4 + (size_t)(s0 + s) * 4096 + 3072 + h * 64 + g * 8;
        ushort8 qv = *(const ushort8*)qc;
        float acc = 0.f;
#pragma unroll
        for (int j = 0; j < 8; j++)
            acc += bf2f(qv[j]) * bk[h * 64 + g * 8 + j];
        acc += __shfl_xor(acc, 1);
        acc += __shfl_xor(acc, 2);
        acc += __shfl_xor(acc, 4);
        if (g == 0) s_c[hh][s] = acc;
    }

    // ---- B: t[hh] = qcol_h @ WkT_h  (16 x 1024), wave w owns n in [w*256,+256) ----
    bf16x8 aq[2][2];
#pragma unroll
    for (int hh = 0; hh < 2; hh++)
#pragma unroll
        for (int kst = 0; kst < 2; kst++)
            aq[hh][kst] = *(const bf16x8*)(qkv4 + (size_t)(s0 + lrow) * 4096 + 3072
                                           + (hg * 2 + hh) * 64 + kst * 32 + lk);
#pragma unroll
    for (int hh = 0; hh < 2; hh++) {
        const int h = hg * 2 + hh;
#pragma unroll
        for (int nt = 0; nt < 16; nt++) {
            const int n = w * 256 + nt * 16;
            floatx4 acc = (floatx4)0.f;
#pragma unroll
            for (int kst = 0; kst < 2; kst++) {
                bf16x8 bw = *(const bf16x8*)(WkT + (size_t)(n + lrow) * 1024
                                             + h * 64 + kst * 32 + lk);
                acc = __builtin_amdgcn_mfma_f32_16x16x32_bf16(aq[hh][kst], bw, acc, 0, 0, 0);
            }
#pragma unroll
            for (int r = 0; r < 4; r++)
                tz[hh][quad * 4 + r][n + lrow] = f32_to_bf16(acc[r]);
        }
    }
    __syncthreads();

    // ---- C: scores S'[s][sl] = t . ri ; wave w: sl in [w*32,+32) ----
    {
        floatx4 sacc[2][2];
#pragma unroll
        for (int ntl = 0; ntl < 2; ntl++)
#pragma unroll
            for (int hh = 0; hh < 2; hh++) sacc[ntl][hh] = (floatx4)0.f;
        for (int kst = 0; kst < 32; kst++) {
            bf16x8 at0 = *(const bf16x8*)&tz[0][lrow][kst * 32 + lk];
            bf16x8 at1 = *(const bf16x8*)&tz[1][lrow][kst * 32 + lk];
#pragma unroll
            for (int ntl = 0; ntl < 2; ntl++) {
                bf16x8 br = *(const bf16x8*)(ri + (size_t)(r0 + w * 32 + ntl * 16 + lrow) * 1024
                                             + kst * 32 + lk);
                sacc[ntl][0] = __builtin_amdgcn_mfma_f32_16x16x32_bf16(at0, br, sacc[ntl][0], 0, 0, 0);
                sacc[ntl][1] = __builtin_amdgcn_mfma_f32_16x16x32_bf16(at1, br, sacc[ntl][1], 0, 0, 0);
            }
        }
        if (quad == w) {
            const int l = lrow & 7, hi = (lrow >> 3) & 1;
#pragma unroll
            for (int ntl = 0; ntl < 2; ntl++) {
                const int s = 4 * w + 2 * ntl + hi;
#pragma unroll
                for (int hh = 0; hh < 2; hh++) {
                    float val = hi ? sacc[ntl][hh][2 * ntl + 1] : sacc[ntl][hh][2 * ntl];
                    s_sc[hh][s][l] = val;
                }
            }
        }
    }
    __syncthreads();

    // ---- D: per-(s,h) softmax partial over the 8 memory keys ----
    if (t < 32) {
        const int hh = t >> 4, s = t & 15;
        const int h = hg * 2 + hh;
        const float c = s_c[hh][s];
        float sc[8], m2 = -1e30f;
#pragma unroll
        for (int l = 0; l < 8; l++) {
            sc[l] = (s_sc[hh][s][l] + c) * SCALE;
            m2 = fmaxf(m2, sc[l]);
        }
        float l2 = 0.f;
#pragma unroll
        for (int l = 0; l < 8; l++) {
            float p = __expf(sc[l] - m2);
            s_p[hh][s][l] = p;
            l2 += p;
        }
        s_l2[hh][s] = l2;
        mlmem[(size_t)h * 2048 + s0 + s] = make_float2(m2, l2);
    }
    __syncthreads();

    // ---- E: z[hh][s][k] = sum_l p ri  (VALU, f32) -> tz (overwrites t) ----
    {
        const int s = t & 15, kc = (t >> 4) * 64;
        float z0[64], z1[64];
#pragma unroll
        for (int j = 0; j < 64; j++) { z0[j] = 0.f; z1[j] = 0.f; }
        for (int l = 0; l < 8; l++) {
            const float p0 = s_p[0][s][l], p1 = s_p[1][s][l];
            const unsigned short* base = ri + (size_t)(r0 + s * 8 + l) * 1024 + kc;
#pragma unroll
            for (int c8 = 0; c8 < 8; c8++) {
                ushort8 v = *(const ushort8*)(base + c8 * 8);
#pragma unroll
                for (int j = 0; j < 8; j++) {
                    float f = bf2f(v[j]);
                    z0[c8 * 8 + j] = fmaf(p0, f, z0[c8 * 8 + j]);
                    z1[c8 * 8 + j] = fmaf(p1, f, z1[c8 * 8 + j]);
                }
            }
        }
        __syncthreads();   // everyone done reading t before overwrite
#pragma unroll
        for (int c8 = 0; c8 < 8; c8++) {
            ushort8 o0, o1;
#pragma unroll
            for (int j = 0; j < 8; j++) {
                o0[j] = f32_to_bf16(z0[c8 * 8 + j]);
                o1[j] = f32_to_bf16(z1[c8 * 8 + j]);
            }
            *(ushort8*)&tz[0][s][kc + c8 * 8] = o0;
            *(ushort8*)&tz[1][s][kc + c8 * 8] = o1;
        }
    }
    __syncthreads();

    // ---- F: O2 = z @ Wv_h^T + l2*bv_h ; wave w: e-tile w ----
    {
        floatx4 oacc[2] = {(floatx4)0.f, (floatx4)0.f};
        for (int kst = 0; kst < 32; kst++) {
            bf16x8 az0 = *(const bf16x8*)&tz[0][lrow][kst * 32 + lk];
            bf16x8 az1 = *(const bf16x8*)&tz[1][lrow][kst * 32 + lk];
            bf16x8 bw0 = *(const bf16x8*)(Wv + (size_t)((hg * 2 + 0) * 64 + w * 16 + lrow) * 1024
                                          + kst * 32 + lk);
            bf16x8 bw1 = *(const bf16x8*)(Wv + (size_t)((hg * 2 + 1) * 64 + w * 16 + lrow) * 1024
                                          + kst * 32 + lk);
            oacc[0] = __builtin_amdgcn_mfma_f32_16x16x32_bf16(az0, bw0, oacc[0], 0, 0, 0);
            oacc[1] = __builtin_amdgcn_mfma_f32_16x16x32_bf16(az1, bw1, oacc[1], 0, 0, 0);
        }
        const int e = w * 16 + lrow;
#pragma unroll
        for (int hh = 0; hh < 2; hh++) {
            const int h = hg * 2 + hh;
            const float bve = bv[h * 64 + e];
#pragma unroll
            for (int r = 0; r < 4; r++) {
                const int s = quad * 4 + r;
                Omem[((size_t)h * 2048 + s0 + s) * 64 + e] =
                    oacc[hh][r] + s_l2[hh][s] * bve;
            }
        }
    }
}

// ---------------------------------------------------------------------------
// Token-attention split kernel (flash, causal). 1024 blocks, balanced.
// ---------------------------------------------------------------------------
__global__ __launch_bounds__(256) void attn_split_kernel(
    const unsigned short* __restrict__ qkv4,
    float* __restrict__ Opart, float2* __restrict__ mlpart)
{
    const int t    = threadIdx.x;
    const int w    = t >> 6, lane = t & 63;
    const int lrow = lane & 15;
    const int lk   = (lane >> 4) * 8;
    const int rrow = (lane >> 4) * 4;
    const int lin  = blockIdx.x;
    const int hs   = lin & 31, g = lin >> 5;
    const int h    = hs >> 1, s = hs & 1;
    const int a    = g & 7, bq = g >> 3;
    const int qt   = (bq == 0) ? a : (bq == 1) ? 15 - a : (bq == 2) ? 16 + a : 31 - a;
    const int q0   = qt * 64;
    const int n    = qt + 1, nh = (n + 1) >> 1;
    const int lo   = s ? nh : 0, hi = s ? n : nh;
    const int part = (h * 32 + qt) * 2 + s;

    __shared__ unsigned short Qs[64 * 72];
    __shared__ unsigned short Ks[64 * 72];
    __shared__ unsigned short Vt[64 * 72];
    __shared__ unsigned short Pb[64 * 72];

#pragma unroll
    for (int p = 0; p < 2; p++) {
        int idx = p * 256 + t;
        int row = idx >> 3, col = (idx & 7) * 8;
        *(bf16x8*)&Qs[row * 72 + col] =
            *(const bf16x8*)(qkv4 + (size_t)(q0 + row) * 4096 + h * HD + col);
    }

    float m_i[4], l_i[4];
    floatx4 Oacc[4];
#pragma unroll
    for (int r = 0; r < 4; r++) { m_i[r] = -1e30f; l_i[r] = 0.f; }
#pragma unroll
    for (int et = 0; et < 4; et++) Oacc[et] = (floatx4)0.f;

    for (int jt = lo; jt < hi; jt++) {
        const int j0 = jt * 64;
#pragma unroll
        for (int p = 0; p < 2; p++) {
            int idx = p * 256 + t;
            int row = idx >> 3, col = (idx & 7) * 8;
            *(bf16x8*)&Ks[row * 72 + col] =
                *(const bf16x8*)(qkv4 + (size_t)(j0 + row) * 4096 + D + h * HD + col);
        }
        {
            const int pr = t & 31, eg = t >> 5;
            const unsigned short* v0 =
                qkv4 + (size_t)(j0 + 2 * pr) * 4096 + 2 * D + h * HD + eg * 8;
            ushort8 va = *(const ushort8*)v0;
            ushort8 vb = *(const ushort8*)(v0 + 4096);
#pragma unroll
            for (int j = 0; j < 8; j++) {
                unsigned int pk = (unsigned int)va[j] | ((unsigned int)vb[j] << 16);
                *(unsigned int*)&Vt[(eg * 8 + j) * 72 + 2 * pr] = pk;
            }
        }
        __syncthreads();

        floatx4 S[4];
#pragma unroll
        for (int nt = 0; nt < 4; nt++) S[nt] = (floatx4)0.f;
#pragma unroll
        for (int kst = 0; kst < 2; kst++) {
            bf16x8 aqf = *(const bf16x8*)&Qs[(w * 16 + lrow) * 72 + kst * 32 + lk];
#pragma unroll
            for (int nt = 0; nt < 4; nt++) {
                bf16x8 bk = *(const bf16x8*)&Ks[(nt * 16 + lrow) * 72 + kst * 32 + lk];
                S[nt] = __builtin_amdgcn_mfma_f32_16x16x32_bf16(aqf, bk, S[nt], 0, 0, 0);
            }
        }

#pragma unroll
        for (int r = 0; r < 4; r++) {
            const int qg = q0 + w * 16 + rrow + r;
            float sc[4];
            float mx = -1e30f;
#pragma unroll
            for (int nt = 0; nt < 4; nt++) {
                sc[nt] = S[nt][r] * SCALE;
                if (j0 + nt * 16 + lrow > qg) sc[nt] = -1e30f;
                mx = fmaxf(mx, sc[nt]);
            }
#pragma unroll
            for (int off = 1; off < 16; off <<= 1)
                mx = fmaxf(mx, __shfl_xor(mx, off));
            if (mx <= -1e29f) {
#pragma unroll
                for (int nt = 0; nt < 4; nt++)
                    Pb[(w * 16 + rrow + r) * 72 + nt * 16 + lrow] = 0;
                continue;
            }
            const float newm  = fmaxf(m_i[r], mx);
            const float alpha = __expf(m_i[r] - newm);
            m_i[r] = newm;
            float ps = 0.f;
#pragma unroll
            for (int nt = 0; nt < 4; nt++) {
                float pe = __expf(sc[nt] - newm);
                ps += pe;
                Pb[(w * 16 + rrow + r) * 72 + nt * 16 + lrow] = f32_to_bf16(pe);
            }
#pragma unroll
            for (int off = 1; off < 16; off <<= 1)
                ps += __shfl_xor(ps, off);
            l_i[r] = l_i[r] * alpha + ps;
#pragma unroll
            for (int et = 0; et < 4; et++) Oacc[et][r] *= alpha;
        }
        __syncthreads();

#pragma unroll
        for (int kst = 0; kst < 2; kst++) {
            bf16x8 ap = *(const bf16x8*)&Pb[(w * 16 + lrow) * 72 + kst * 32 + lk];
#pragma unroll
            for (int et = 0; et < 4; et++) {
                bf16x8 bv = *(const bf16x8*)&Vt[(et * 16 + lrow) * 72 + kst * 32 + lk];
                Oacc[et] = __builtin_amdgcn_mfma_f32_16x16x32_bf16(ap, bv, Oacc[et], 0, 0, 0);
            }
        }
        __syncthreads();
    }

#pragma unroll
    for (int r = 0; r < 4; r++) {
        const int ql = w * 16 + rrow + r;
        if (lrow == 0) mlpart[(size_t)part * 64 + ql] = make_float2(m_i[r], l_i[r]);
#pragma unroll
        for (int et = 0; et < 4; et++)
            Opart[((size_t)part * 64 + ql) * 64 + et * 16 + lrow] = Oacc[et][r];
    }
}

// ---------------------------------------------------------------------------
// merge: 3-way softmax-split combine (tok0, tok1, mem) -> ctx (bf16)
// ---------------------------------------------------------------------------
__global__ __launch_bounds__(256) void attn_merge_kernel(
    const float* __restrict__ Opart, const float2* __restrict__ mlpart,
    const float* __restrict__ Omem, const float2* __restrict__ mlmem,
    unsigned short* __restrict__ ctx)
{
    const int blk = blockIdx.x;            // h*32 + qt
    const int h = blk >> 5, qt = blk & 31;
    const int q0 = qt * 64;
    const int t = threadIdx.x, tx = t & 15, ty = t >> 4;
    const size_t p0 = (size_t)blk * 2, p1 = p0 + 1;
#pragma unroll
    for (int i = 0; i < 4; i++) {
        const int qi = ty * 4 + i, qg = q0 + qi;
        float2 ml0 = mlpart[p0 * 64 + qi];
        float2 ml1 = mlpart[p1 * 64 + qi];
        float2 mlm = mlmem[(size_t)h * 2048 + qg];
        const float M  = fmaxf(fmaxf(ml0.x, ml1.x), mlm.x);
        const float f0 = __expf(ml0.x - M), f1 = __expf(ml1.x - M), fm = __expf(mlm.x - M);
        const float rl = 1.f / (ml0.y * f0 + ml1.y * f1 + mlm.y * fm);
        float4 o0 = *(const float4*)&Opart[(p0 * 64 + qi) * 64 + tx * 4];
        float4 o1 = *(const float4*)&Opart[(p1 * 64 + qi) * 64 + tx * 4];
        float4 om = *(const float4*)&Omem[((size_t)h * 2048 + qg) * 64 + tx * 4];
        ushort4 ob;
        ob.x = f32_to_bf16((o0.x * f0 + o1.x * f1 + om.x * fm) * rl);
        ob.y = f32_to_bf16((o0.y * f0 + o1.y * f1 + om.y * fm) * rl);
        ob.z = f32_to_bf16((o0.z * f0 + o1.z * f1 + om.z * fm) * rl);
        ob.w = f32_to_bf16((o0.w * f0 + o1.w * f1 + om.w * fm) * rl);
        *(ushort4*)(ctx + (size_t)qg * D + h * HD + tx * 4) = ob;
    }
}

// ---------------------------------------------------------------------------
extern "C" void kernel_launch(void* const* d_in, const int* in_sizes, int n_in,
                              void* d_out, int out_size, void* d_ws, size_t ws_size,
                              hipStream_t stream)
{
    const float* x    = (const float*)d_in[0];
    const float* pv   = (const float*)d_in[1];
    const float* Wqkv = (const float*)d_in[2];
    const float* bqkv = (const float*)d_in[3];
    const float* Wcol = (const float*)d_in[4];
    const float* bcol = (const float*)d_in[5];
    const float* Wout = (const float*)d_in[6];
    const float* bout = (const float*)d_in[7];
    float* out = (float*)d_out;

    char* p = (char*)d_ws;
    unsigned short* x_bf    = (unsigned short*)p; p += (size_t)2048 * 1024 * 2;
    unsigned short* W4_bf   = (unsigned short*)p; p += (size_t)4096 * 1024 * 2;   // Wqkv|Wcol
    unsigned short* Wout_bf = (unsigned short*)p; p += (size_t)1024 * 1024 * 2;
    float*          b4      = (float*)p;          p += (size_t)4096 * 4;
    unsigned short* WkT_bf  = (unsigned short*)p; p += (size_t)1024 * 1024 * 2;
    unsigned short* ri_bf   = (unsigned short*)p; p += (size_t)16384 * 1024 * 2;
    unsigned short* qkv4_bf = (unsigned short*)p; p += (size_t)2048 * 4096 * 2;   // Q|K|V|Qcol
    unsigned short* ctx_bf  = (unsigned short*)p; p += (size_t)2048 * 1024 * 2;
    float*          Opart   = (float*)p;          p += (size_t)1024 * 64 * 64 * 4;
    float2*         mlpart  = (float2*)p;         p += (size_t)1024 * 64 * 8;
    float*          Omem    = (float*)p;          p += (size_t)16 * 2048 * 64 * 4;
    float2*         mlmem   = (float2*)p;         p += (size_t)16 * 2048 * 8;
    // ~97 MB total

    prep_kernel<<<PREP_GRID, 256, 0, stream>>>(pv, x, Wqkv, Wcol, Wout, bqkv, bcol,
                                               ri_bf, x_bf, W4_bf, Wout_bf, b4, WkT_bf);
    // qkv4 = x @ [Wqkv|Wcol]^T + [bqkv|bcol]
    gemm_bf16_kernel<unsigned short><<<dim3(32, 16), 256, 0, stream>>>(
        x_bf, W4_bf, b4, qkv4_bf, 1024, 4096);
    // token attention splits
    attn_split_kernel<<<1024, 256, 0, stream>>>(qkv4_bf, Opart, mlpart);
    // memory-key attention partial (replaces the 68.7 GF rkv GEMM)
    mem_attn_kernel<<<1024, 256, 0, stream>>>(
        qkv4_bf, ri_bf, WkT_bf, W4_bf + (size_t)2048 * 1024,
        bqkv + 1024, bqkv + 2048, Omem, mlmem);
    // 3-way merge
    attn_merge_kernel<<<512, 256, 0, stream>>>(Opart, mlpart, Omem, mlmem, ctx_bf);
    // out = ctx @ Wout^T + bout
    gemm_bf16_kernel<float><<<dim3(8, 16), 256, 0, stream>>>(
        ctx_bf, Wout_bf, bout, out, 1024, 1024);
}